// Round 1
// 99.438 us; speedup vs baseline: 1.1095x; 1.1095x over previous
//
#include <hip/hip_runtime.h>
#include <math.h>

// Default: no FMA contraction — KNN distance order and the LAPACK-faithful
// eigh path must match the reference bitwise. The tolerant PPF path opts
// back into contract(fast) locally.
#pragma clang fp contract(off)

#define NPTS 2048
#define KNN 10
#define NOUT 256

// ---------------- LAPACK-faithful fp32 helpers ----------------

__device__ __forceinline__ float lapy2f(float x, float y) {
  float xa = fabsf(x), ya = fabsf(y);
  float w = fmaxf(xa, ya), z = fminf(xa, ya);
  if (z == 0.f) return w;
  float t = z / w;
  return w * sqrtf(1.f + t * t);
}

// SLARTG, LAPACK >= 3.10 convention (modern OpenBLAS / numpy wheels).
__device__ __forceinline__ void slartgf(float f, float g, float& c, float& s, float& r) {
  if (g == 0.f) { c = 1.f; s = 0.f; r = f; }
  else if (f == 0.f) { c = 0.f; s = copysignf(1.f, g); r = fabsf(g); }
  else {
    float d = sqrtf(f * f + g * g);
    float p = 1.f / d;
    c = fabsf(f) * p;
    s = g * copysignf(p, f);
    r = copysignf(d, f);
  }
}

__device__ __forceinline__ void slaev2f(float a, float b, float c,
                                        float& rt1, float& rt2, float& cs1, float& sn1) {
  float sm = a + c;
  float df = a - c;
  float adf = fabsf(df);
  float tb = b + b;
  float ab = fabsf(tb);
  float acmx, acmn;
  if (fabsf(a) > fabsf(c)) { acmx = a; acmn = c; } else { acmx = c; acmn = a; }
  float rt;
  if (adf > ab)      { float t = ab / adf; rt = adf * sqrtf(1.f + t * t); }
  else if (adf < ab) { float t = adf / ab; rt = ab * sqrtf(1.f + t * t); }
  else               { rt = ab * sqrtf(2.f); }
  int sgn1;
  if (sm < 0.f) {
    rt1 = 0.5f * (sm - rt); sgn1 = -1;
    rt2 = (acmx / rt1) * acmn - (b / rt1) * b;
  } else if (sm > 0.f) {
    rt1 = 0.5f * (sm + rt); sgn1 = 1;
    rt2 = (acmx / rt1) * acmn - (b / rt1) * b;
  } else {
    rt1 = 0.5f * rt; rt2 = -0.5f * rt; sgn1 = 1;
  }
  int sgn2; float cs;
  if (df >= 0.f) { cs = df + rt; sgn2 = 1; } else { cs = df - rt; sgn2 = -1; }
  float acs = fabsf(cs);
  if (acs > ab) {
    float ct = -tb / cs;
    sn1 = 1.f / sqrtf(1.f + ct * ct);
    cs1 = ct * sn1;
  } else {
    if (ab == 0.f) { cs1 = 1.f; sn1 = 0.f; }
    else {
      float tn = -cs / tb;
      cs1 = 1.f / sqrtf(1.f + tn * tn);
      sn1 = tn * cs1;
    }
  }
  if (sgn1 == sgn2) { float tn = cs1; cs1 = -sn1; sn1 = tn; }
}

// Column rotations on the scalarized 3x3 eigenvector matrix (z[row][col]).
#define ROT12(c, s) {                                         \
    float t_;                                                 \
    t_ = z01; z01 = (c) * t_ - (s) * z00; z00 = (s) * t_ + (c) * z00; \
    t_ = z11; z11 = (c) * t_ - (s) * z10; z10 = (s) * t_ + (c) * z10; \
    t_ = z21; z21 = (c) * t_ - (s) * z20; z20 = (s) * t_ + (c) * z20; }
#define ROT23(c, s) {                                         \
    float t_;                                                 \
    t_ = z02; z02 = (c) * t_ - (s) * z01; z01 = (s) * t_ + (c) * z01; \
    t_ = z12; z12 = (c) * t_ - (s) * z11; z11 = (s) * t_ + (c) * z11; \
    t_ = z22; z22 = (c) * t_ - (s) * z21; z21 = (s) * t_ + (c) * z21; }

// SSTEQR('I', n=3), fully scalarized: all state in VGPRs, zero scratch.
__device__ __forceinline__ void ssteqr3_reg(
    float& d0, float& d1, float& d2, float& e0, float& e1,
    float& z00, float& z01, float& z02,
    float& z10, float& z11, float& z12,
    float& z20, float& z21, float& z22) {
  const float eps = 5.9604645e-8f;
  const float eps2 = eps * eps;
  const float safmin = 1.1754944e-38f;
  const int nmaxit = 90;
  int jtot = 0;
  int l1 = 1;
  for (int og = 0; og < 4; ++og) {
    if (l1 > 3) break;
    if (l1 == 2) e0 = 0.f;
    else if (l1 == 3) e1 = 0.f;
    int m = 3;
    if (l1 == 1) {
      float t = fabsf(e0);
      if (t == 0.f) m = 1;
      else if (t <= (sqrtf(fabsf(d0)) * sqrtf(fabsf(d1))) * eps) { e0 = 0.f; m = 1; }
      else {
        float t2 = fabsf(e1);
        if (t2 == 0.f) m = 2;
        else if (t2 <= (sqrtf(fabsf(d1)) * sqrtf(fabsf(d2))) * eps) { e1 = 0.f; m = 2; }
      }
    } else if (l1 == 2) {
      float t = fabsf(e1);
      if (t == 0.f) m = 2;
      else if (t <= (sqrtf(fabsf(d1)) * sqrtf(fabsf(d2))) * eps) { e1 = 0.f; m = 2; }
    }
    int l = l1, lend = m;
    l1 = m + 1;
    if (lend == l) continue;
    {
      float dlend = (lend == 1) ? d0 : ((lend == 2) ? d1 : d2);
      float dl = (l == 1) ? d0 : ((l == 2) ? d1 : d2);
      if (fabsf(dlend) < fabsf(dl)) { int t = lend; lend = l; l = t; }
    }
    if (lend > l) {
      // ---- QL iteration ----
      for (int it = 0; it < 128; ++it) {
        int m2 = lend;
        if (l != lend) {
          for (int mm = l; mm <= lend - 1; ++mm) {
            float em  = (mm == 1) ? e0 : e1;
            float dm1 = (mm == 1) ? d0 : d1;
            float dm  = (mm == 1) ? d1 : d2;
            float tst = em * em;
            if (tst <= (eps2 * fabsf(dm1)) * fabsf(dm) + safmin) { m2 = mm; break; }
          }
        }
        if (m2 < lend) { if (m2 == 1) e0 = 0.f; else e1 = 0.f; }
        float p = (l == 1) ? d0 : ((l == 2) ? d1 : d2);
        if (m2 == l) { l += 1; if (l <= lend) continue; break; }
        if (m2 == l + 1) {
          float rt1, rt2, c, s;
          if (l == 1) {
            slaev2f(d0, e0, d1, rt1, rt2, c, s);
            ROT12(c, s)
            d0 = rt1; d1 = rt2; e0 = 0.f;
          } else {
            slaev2f(d1, e1, d2, rt1, rt2, c, s);
            ROT23(c, s)
            d1 = rt1; d2 = rt2; e1 = 0.f;
          }
          l += 2; if (l <= lend) continue; break;
        }
        if (jtot == nmaxit) break;
        jtot++;
        // full QL step: l=1, m2=3, lend=3
        float g = (d1 - p) / (2.f * e0);
        float r = lapy2f(g, 1.f);
        g = d2 - p + e0 / (g + copysignf(r, g));
        float s = 1.f, c = 1.f;
        p = 0.f;
        float c0, s0n, c1, s1n;
        {  // i = 2
          float f = s * e1;
          float bb = c * e1;
          slartgf(g, f, c, s, r);
          g = d2 - p;
          r = (d1 - g) * s + 2.f * c * bb;
          p = s * r;
          d2 = g + p;
          g = c * r - bb;
          c1 = c; s1n = -s;
        }
        {  // i = 1
          float f = s * e0;
          float bb = c * e0;
          slartgf(g, f, c, s, r);
          e1 = r;
          g = d1 - p;
          r = (d0 - g) * s + 2.f * c * bb;
          p = s * r;
          d1 = g + p;
          g = c * r - bb;
          c0 = c; s0n = -s;
        }
        ROT23(c1, s1n)
        ROT12(c0, s0n)
        d0 = d0 - p;
        e0 = g;
      }
    } else {
      // ---- QR iteration ----
      for (int it = 0; it < 128; ++it) {
        int m2 = lend;
        if (l != lend) {
          for (int mm = l; mm >= lend + 1; --mm) {
            float em  = (mm == 3) ? e1 : e0;
            float dm1 = (mm == 3) ? d2 : d1;
            float dm2 = (mm == 3) ? d1 : d0;
            float tst = em * em;
            if (tst <= (eps2 * fabsf(dm1)) * fabsf(dm2) + safmin) { m2 = mm; break; }
          }
        }
        if (m2 > lend) { if (m2 == 3) e1 = 0.f; else e0 = 0.f; }
        float p = (l == 1) ? d0 : ((l == 2) ? d1 : d2);
        if (m2 == l) { l -= 1; if (l >= lend) continue; break; }
        if (m2 == l - 1) {
          float rt1, rt2, c, s;
          if (l == 2) {
            slaev2f(d0, e0, d1, rt1, rt2, c, s);
            ROT12(c, s)
            d0 = rt1; d1 = rt2; e0 = 0.f;
          } else {
            slaev2f(d1, e1, d2, rt1, rt2, c, s);
            ROT23(c, s)
            d1 = rt1; d2 = rt2; e1 = 0.f;
          }
          l -= 2; if (l >= lend) continue; break;
        }
        if (jtot == nmaxit) break;
        jtot++;
        // full QR step: l=3, m2=1, lend=1
        float g = (d1 - p) / (2.f * e1);
        float r = lapy2f(g, 1.f);
        g = d0 - p + e1 / (g + copysignf(r, g));
        float s = 1.f, c = 1.f;
        p = 0.f;
        float c0, s0p, c1, s1p;
        {  // i = 1
          float f = s * e0;
          float bb = c * e0;
          slartgf(g, f, c, s, r);
          g = d0 - p;
          r = (d1 - g) * s + 2.f * c * bb;
          p = s * r;
          d0 = g + p;
          g = c * r - bb;
          c0 = c; s0p = s;
        }
        {  // i = 2
          float f = s * e1;
          float bb = c * e1;
          slartgf(g, f, c, s, r);
          e0 = r;
          g = d1 - p;
          r = (d2 - g) * s + 2.f * c * bb;
          p = s * r;
          d1 = g + p;
          g = c * r - bb;
          c1 = c; s1p = s;
        }
        ROT12(c0, s0p)
        ROT23(c1, s1p)
        d2 = d2 - p;
        e1 = g;
      }
    }
  }
  // ascending eigenvalue selection sort with column swaps
  {
    int k = 1; float p = d0;
    if (d1 < p) { k = 2; p = d1; }
    if (d2 < p) { k = 3; p = d2; }
    if (k == 2) {
      d1 = d0; d0 = p;
      float t;
      t = z00; z00 = z01; z01 = t;
      t = z10; z10 = z11; z11 = t;
      t = z20; z20 = z21; z21 = t;
    } else if (k == 3) {
      d2 = d0; d0 = p;
      float t;
      t = z00; z00 = z02; z02 = t;
      t = z10; z10 = z12; z12 = t;
      t = z20; z20 = z22; z22 = t;
    }
    k = 2; p = d1;
    if (d2 < p) { k = 3; p = d2; }
    if (k == 3) {
      d2 = d1; d1 = p;
      float t;
      t = z01; z01 = z02; z02 = t;
      t = z11; z11 = z12; z12 = t;
      t = z21; z21 = z22; z22 = t;
    }
  }
}

// ---------------- Kernel 1: KNN (block-per-point, 4 cooperating waves) ----------------
// 2048 blocks x 256 threads (8192 waves = 32 waves/CU vs previous 8/CU).
// Wave wv handles the 512-j slice [wv*512, wv*512+512): 8 candidates/lane in
// one sorted-8 array, then 11 rounds of wave-wide u64-min extraction gives
// the wave's top-11. Rank-based merge of the 4x11 candidates in LDS
// reproduces top_k's (distance, index) tie order exactly (u64 keys unique,
// strict '<' rank). Distance math and the full eigh path are bitwise
// identical to the validated R4 kernel; eigh runs once per block (thread 0).

__global__ __launch_bounds__(256) void knn_normals_kernel(
    const float* __restrict__ pts,
    float* __restrict__ pxa, float* __restrict__ pya, float* __restrict__ pza,
    float* __restrict__ nxa, float* __restrict__ nya, float* __restrict__ nza) {
  __shared__ unsigned long long cand[4 * (KNN + 1)];
  __shared__ int knn_sh[KNN];
  const int tid = threadIdx.x;
  const int lane = tid & 63;
  const int wv = tid >> 6;
  const int p = blockIdx.x;

  {
    float px = pts[3 * p], py = pts[3 * p + 1], pz = pts[3 * p + 2];
    if (tid == 0) { pxa[p] = px; pya[p] = py; pza[p] = pz; }

    unsigned long long k0[8];
#pragma unroll
    for (int t = 0; t < 8; ++t) {
      int j = wv * 512 + t * 64 + lane;
      float dx = px - pts[3 * j];
      float dy = py - pts[3 * j + 1];
      float dz = pz - pts[3 * j + 2];
      float sq = dx * dx;
      sq = sq + dy * dy;
      sq = sq + dz * dz;
      k0[t] = (((unsigned long long)__float_as_uint(sq)) << 32) |
              (unsigned int)j;
    }

#define CE(a, b)                                                          \
    {                                                                     \
      unsigned long long lo = k0[a] < k0[b] ? k0[a] : k0[b];              \
      unsigned long long hi = k0[a] < k0[b] ? k0[b] : k0[a];              \
      k0[a] = lo; k0[b] = hi;                                             \
    }
    CE(0, 1) CE(2, 3) CE(4, 5) CE(6, 7)
    CE(0, 2) CE(1, 3) CE(4, 6) CE(5, 7)
    CE(1, 2) CE(5, 6) CE(0, 4) CE(3, 7)
    CE(1, 5) CE(2, 6)
    CE(1, 4) CE(3, 6)
    CE(2, 4) CE(3, 5)
    CE(3, 4)
#undef CE

    // 11 rounds: extract this wave's top-11 (keys unique -> single winner).
    for (int r = 0; r < KNN + 1; ++r) {
      unsigned long long m = k0[0];
#pragma unroll
      for (int off = 32; off > 0; off >>= 1) {
        unsigned long long o = __shfl_xor(m, off, 64);
        m = (o < m) ? o : m;
      }
      if (lane == 0) cand[wv * (KNN + 1) + r] = m;
      if (k0[0] == m) {
#pragma unroll
        for (int q = 0; q < 7; ++q) k0[q] = k0[q + 1];
        k0[7] = 0xFFFFFFFFFFFFFFFFULL;
      }
    }
  }
  __syncthreads();

  // Rank-merge the 44 candidates (all within wave 0; LDS broadcast reads).
  // Global rank 0 is the point itself (dist 0); ranks 1..10 are the KNN in
  // exactly top_k order.
  if (tid < 4 * (KNN + 1)) {
    unsigned long long e = cand[tid];
    int rank = 0;
#pragma unroll
    for (int m = 0; m < 4 * (KNN + 1); ++m) rank += (cand[m] < e) ? 1 : 0;
    if (rank > 0 && rank <= KNN)
      knn_sh[rank - 1] = (int)(unsigned int)(e & 0xFFFFFFFFULL);
  }
  __syncthreads();

  // ---- covariance + eigh for this block's point (thread 0) ----
  if (tid == 0) {
    float nx[KNN], ny[KNN], nz[KNN];
    float sx = 0.f, sy = 0.f, sz = 0.f;
#pragma unroll
    for (int t = 0; t < KNN; ++t) {
      int j = knn_sh[t];
      nx[t] = pts[3 * j]; ny[t] = pts[3 * j + 1]; nz[t] = pts[3 * j + 2];
      sx = sx + nx[t]; sy = sy + ny[t]; sz = sz + nz[t];
    }
    float mx = sx / 10.f, my = sy / 10.f, mz = sz / 10.f;
    float a11 = 0.f, a21 = 0.f, a31 = 0.f, a22 = 0.f, a32 = 0.f, a33 = 0.f;
#pragma unroll
    for (int t = 0; t < KNN; ++t) {
      float cx = nx[t] - mx, cy = ny[t] - my, cz = nz[t] - mz;
      a11 = a11 + cx * cx;
      a21 = a21 + cy * cx;
      a31 = a31 + cz * cx;
      a22 = a22 + cy * cy;
      a32 = a32 + cz * cy;
      a33 = a33 + cz * cz;
    }
    a11 = a11 / 10.f; a21 = a21 / 10.f; a31 = a31 / 10.f;
    a22 = a22 / 10.f; a32 = a32 / 10.f; a33 = a33 / 10.f;

    // SSYTD2 (uplo='L', n=3)
    float d0, d1, d2, e0, e1, tau1 = 0.f, v2 = 0.f;
    {
      float alpha = a21;
      float xnorm = fabsf(a31);
      if (xnorm == 0.f) {
        tau1 = 0.f; v2 = 0.f;
        d0 = a11; d1 = a22; d2 = a33; e0 = alpha; e1 = a32;
      } else {
        float beta = -copysignf(lapy2f(alpha, xnorm), alpha);
        tau1 = (beta - alpha) / beta;
        v2 = a31 * (1.f / (alpha - beta));  // DSCAL: reciprocal then multiply
        float y1 = tau1 * a22; y1 = y1 + tau1 * (a32 * v2);
        float y2 = tau1 * a32; y2 = y2 + (tau1 * v2) * a33;
        float dotv = y1; dotv = dotv + y2 * v2;
        float ac = -0.5f * tau1 * dotv;
        y1 = y1 + ac;
        y2 = y2 + ac * v2;
        float t1 = -y1, t2 = -1.f;
        a22 = (a22 + t1) + y1 * t2;
        a32 = (a32 + v2 * t1) + y2 * t2;
        float t1b = -y2, t2b = -v2;
        a33 = (a33 + v2 * t1b) + y2 * t2b;
        d0 = a11; d1 = a22; d2 = a33; e0 = beta; e1 = a32;
      }
    }
    float z00 = 1.f, z01 = 0.f, z02 = 0.f;
    float z10 = 0.f, z11 = 1.f, z12 = 0.f;
    float z20 = 0.f, z21 = 0.f, z22 = 1.f;
    ssteqr3_reg(d0, d1, d2, e0, e1,
                z00, z01, z02, z10, z11, z12, z20, z21, z22);
    if (tau1 != 0.f) {
      float w = tau1 * (z10 + v2 * z20);
      z10 = z10 - w;
      z20 = z20 - v2 * w;
    }
    nxa[p] = z00;
    nya[p] = z10;
    nza[p] = z20;
  }
}

// ---------------- Kernel 2: PPF, block-per-point ----------------
// 2048 blocks x 256 threads (32 waves/CU). Wave wv handles j-slice
// [wv*512, wv*512+512) (8 coalesced SoA iters/lane); wave butterfly, then
// 4-partial LDS reduce; each thread emits one of the 256 outputs.

__device__ __forceinline__ float atan2_pos(float y, float x) {
#pragma clang fp contract(fast)
  // y >= 0; returns atan2(y, x) in [0, pi]; |err| <= 1e-5 rad
  float axx = fabsf(x);
  float mn = fminf(axx, y), mx = fmaxf(axx, y);
  float a = mn * __builtin_amdgcn_rcpf(mx);
  a = (mx == 0.f) ? 0.f : a;
  float s = a * a;
  float r = a * (0.9998660f +
           s * (-0.3302995f +
           s * (0.1801410f +
           s * (-0.0851330f +
           s * 0.0208351f))));
  r = (y > axx) ? 1.57079632679f - r : r;
  r = (x < 0.f) ? 3.14159265359f - r : r;
  return r;
}

__device__ __forceinline__ float angle3(float ax, float ay, float az,
                                        float bx, float by, float bz) {
#pragma clang fp contract(fast)
  float cx = ay * bz - az * by;
  float cy = az * bx - ax * bz;
  float cz = ax * by - ay * bx;
  float sq = cx * cx + cy * cy + cz * cz;
  float dot = ax * bx + ay * by + az * bz;
  // 1-ulp v_sqrt_f32 (tolerant path; avoids the correctly-rounded fixup seq)
  return atan2_pos(__builtin_amdgcn_sqrtf(sq), dot);
}

__global__ __launch_bounds__(256) void ppf_kernel(
    const float* __restrict__ pxa, const float* __restrict__ pya,
    const float* __restrict__ pza, const float* __restrict__ nxa,
    const float* __restrict__ nya, const float* __restrict__ nza,
    const float* __restrict__ Wm, const float* __restrict__ bias,
    float* __restrict__ out) {
#pragma clang fp contract(fast)
  __shared__ float ps[4][4];
  const int tid = threadIdx.x;
  const int lane = tid & 63;
  const int wv = tid >> 6;
  const int i = blockIdx.x;

  float pxi = pxa[i], pyi = pya[i], pzi = pza[i];
  float ax = nxa[i], ay = nya[i], az = nza[i];

  float s0 = 0.f, s1 = 0.f, s2 = 0.f, s3 = 0.f;
#pragma unroll
  for (int it = 0; it < 8; ++it) {
    int j = wv * 512 + it * 64 + lane;
    float dx = pxi - pxa[j];
    float dy = pyi - pya[j];
    float dz = pzi - pza[j];
    float bx = nxa[j], by = nya[j], bz = nza[j];
    float sq = dx * dx + dy * dy + dz * dz;
    s0 += __builtin_amdgcn_sqrtf(sq);
    s1 += angle3(ax, ay, az, dx, dy, dz);
    s2 += angle3(bx, by, bz, dx, dy, dz);
    s3 += angle3(ax, ay, az, bx, by, bz);
  }

  // wave butterfly reduce, then cross-wave reduce via 4x4 LDS partials
#pragma unroll
  for (int off = 1; off < 64; off <<= 1) {
    s0 += __shfl_xor(s0, off, 64);
    s1 += __shfl_xor(s1, off, 64);
    s2 += __shfl_xor(s2, off, 64);
    s3 += __shfl_xor(s3, off, 64);
  }
  if (lane == 0) { ps[wv][0] = s0; ps[wv][1] = s1; ps[wv][2] = s2; ps[wv][3] = s3; }
  __syncthreads();

  const float inv = 1.f / 2048.f;  // power of two: identical to /2048
  float f0 = ((ps[0][0] + ps[1][0]) + (ps[2][0] + ps[3][0])) * inv;
  float f1 = ((ps[0][1] + ps[1][1]) + (ps[2][1] + ps[3][1])) * inv;
  float f2 = ((ps[0][2] + ps[1][2]) + (ps[2][2] + ps[3][2])) * inv;
  float f3 = ((ps[0][3] + ps[1][3]) + (ps[2][3] + ps[3][3])) * inv;

  // epilogue: one output per thread (W row = exactly one float4)
  float4 w = ((const float4*)Wm)[tid];
  float r = (((f0 * w.x + f1 * w.y) + f2 * w.z) + f3 * w.w) + bias[tid];
  out[(size_t)i * NOUT + tid] = r;
}

// ---------------- launcher ----------------

extern "C" void kernel_launch(void* const* d_in, const int* in_sizes, int n_in,
                              void* d_out, int out_size, void* d_ws, size_t ws_size,
                              hipStream_t stream) {
  const float* pts = (const float*)d_in[0];   // (1,2048,3) fp32
  const float* Wm  = (const float*)d_in[1];   // (256,4) fp32
  const float* bs  = (const float*)d_in[2];   // (256,) fp32
  float* out = (float*)d_out;                 // (1,2048,256) fp32

  float* pxa = (float*)d_ws;                  // 6 SoA arrays of 2048 floats
  float* pya = pxa + NPTS;
  float* pza = pya + NPTS;
  float* nxa = pza + NPTS;
  float* nya = nxa + NPTS;
  float* nza = nya + NPTS;

  knn_normals_kernel<<<NPTS, 256, 0, stream>>>(pts, pxa, pya, pza, nxa, nya, nza);
  ppf_kernel<<<NPTS, 256, 0, stream>>>(pxa, pya, pza, nxa, nya, nza, Wm, bs, out);
}

// Round 2
// 95.556 us; speedup vs baseline: 1.1546x; 1.0406x over previous
//
#include <hip/hip_runtime.h>
#include <math.h>

// Default: no FMA contraction — KNN distance order and the LAPACK-faithful
// eigh path must match the reference bitwise. The tolerant PPF path opts
// back into contract(fast) locally.
#pragma clang fp contract(off)

#define NPTS 2048
#define KNN 10
#define NOUT 256

// ---------------- LAPACK-faithful fp32 helpers ----------------

__device__ __forceinline__ float lapy2f(float x, float y) {
  float xa = fabsf(x), ya = fabsf(y);
  float w = fmaxf(xa, ya), z = fminf(xa, ya);
  if (z == 0.f) return w;
  float t = z / w;
  return w * sqrtf(1.f + t * t);
}

// SLARTG, LAPACK >= 3.10 convention (modern OpenBLAS / numpy wheels).
__device__ __forceinline__ void slartgf(float f, float g, float& c, float& s, float& r) {
  if (g == 0.f) { c = 1.f; s = 0.f; r = f; }
  else if (f == 0.f) { c = 0.f; s = copysignf(1.f, g); r = fabsf(g); }
  else {
    float d = sqrtf(f * f + g * g);
    float p = 1.f / d;
    c = fabsf(f) * p;
    s = g * copysignf(p, f);
    r = copysignf(d, f);
  }
}

__device__ __forceinline__ void slaev2f(float a, float b, float c,
                                        float& rt1, float& rt2, float& cs1, float& sn1) {
  float sm = a + c;
  float df = a - c;
  float adf = fabsf(df);
  float tb = b + b;
  float ab = fabsf(tb);
  float acmx, acmn;
  if (fabsf(a) > fabsf(c)) { acmx = a; acmn = c; } else { acmx = c; acmn = a; }
  float rt;
  if (adf > ab)      { float t = ab / adf; rt = adf * sqrtf(1.f + t * t); }
  else if (adf < ab) { float t = adf / ab; rt = ab * sqrtf(1.f + t * t); }
  else               { rt = ab * sqrtf(2.f); }
  int sgn1;
  if (sm < 0.f) {
    rt1 = 0.5f * (sm - rt); sgn1 = -1;
    rt2 = (acmx / rt1) * acmn - (b / rt1) * b;
  } else if (sm > 0.f) {
    rt1 = 0.5f * (sm + rt); sgn1 = 1;
    rt2 = (acmx / rt1) * acmn - (b / rt1) * b;
  } else {
    rt1 = 0.5f * rt; rt2 = -0.5f * rt; sgn1 = 1;
  }
  int sgn2; float cs;
  if (df >= 0.f) { cs = df + rt; sgn2 = 1; } else { cs = df - rt; sgn2 = -1; }
  float acs = fabsf(cs);
  if (acs > ab) {
    float ct = -tb / cs;
    sn1 = 1.f / sqrtf(1.f + ct * ct);
    cs1 = ct * sn1;
  } else {
    if (ab == 0.f) { cs1 = 1.f; sn1 = 0.f; }
    else {
      float tn = -cs / tb;
      cs1 = 1.f / sqrtf(1.f + tn * tn);
      sn1 = tn * cs1;
    }
  }
  if (sgn1 == sgn2) { float tn = cs1; cs1 = -sn1; sn1 = tn; }
}

// Column rotations on the scalarized 3x3 eigenvector matrix (z[row][col]).
#define ROT12(c, s) {                                         \
    float t_;                                                 \
    t_ = z01; z01 = (c) * t_ - (s) * z00; z00 = (s) * t_ + (c) * z00; \
    t_ = z11; z11 = (c) * t_ - (s) * z10; z10 = (s) * t_ + (c) * z10; \
    t_ = z21; z21 = (c) * t_ - (s) * z20; z20 = (s) * t_ + (c) * z20; }
#define ROT23(c, s) {                                         \
    float t_;                                                 \
    t_ = z02; z02 = (c) * t_ - (s) * z01; z01 = (s) * t_ + (c) * z01; \
    t_ = z12; z12 = (c) * t_ - (s) * z11; z11 = (s) * t_ + (c) * z11; \
    t_ = z22; z22 = (c) * t_ - (s) * z21; z21 = (s) * t_ + (c) * z21; }

// SSTEQR('I', n=3), fully scalarized: all state in VGPRs, zero scratch.
__device__ __forceinline__ void ssteqr3_reg(
    float& d0, float& d1, float& d2, float& e0, float& e1,
    float& z00, float& z01, float& z02,
    float& z10, float& z11, float& z12,
    float& z20, float& z21, float& z22) {
  const float eps = 5.9604645e-8f;
  const float eps2 = eps * eps;
  const float safmin = 1.1754944e-38f;
  const int nmaxit = 90;
  int jtot = 0;
  int l1 = 1;
  for (int og = 0; og < 4; ++og) {
    if (l1 > 3) break;
    if (l1 == 2) e0 = 0.f;
    else if (l1 == 3) e1 = 0.f;
    int m = 3;
    if (l1 == 1) {
      float t = fabsf(e0);
      if (t == 0.f) m = 1;
      else if (t <= (sqrtf(fabsf(d0)) * sqrtf(fabsf(d1))) * eps) { e0 = 0.f; m = 1; }
      else {
        float t2 = fabsf(e1);
        if (t2 == 0.f) m = 2;
        else if (t2 <= (sqrtf(fabsf(d1)) * sqrtf(fabsf(d2))) * eps) { e1 = 0.f; m = 2; }
      }
    } else if (l1 == 2) {
      float t = fabsf(e1);
      if (t == 0.f) m = 2;
      else if (t <= (sqrtf(fabsf(d1)) * sqrtf(fabsf(d2))) * eps) { e1 = 0.f; m = 2; }
    }
    int l = l1, lend = m;
    l1 = m + 1;
    if (lend == l) continue;
    {
      float dlend = (lend == 1) ? d0 : ((lend == 2) ? d1 : d2);
      float dl = (l == 1) ? d0 : ((l == 2) ? d1 : d2);
      if (fabsf(dlend) < fabsf(dl)) { int t = lend; lend = l; l = t; }
    }
    if (lend > l) {
      // ---- QL iteration ----
      for (int it = 0; it < 128; ++it) {
        int m2 = lend;
        if (l != lend) {
          for (int mm = l; mm <= lend - 1; ++mm) {
            float em  = (mm == 1) ? e0 : e1;
            float dm1 = (mm == 1) ? d0 : d1;
            float dm  = (mm == 1) ? d1 : d2;
            float tst = em * em;
            if (tst <= (eps2 * fabsf(dm1)) * fabsf(dm) + safmin) { m2 = mm; break; }
          }
        }
        if (m2 < lend) { if (m2 == 1) e0 = 0.f; else e1 = 0.f; }
        float p = (l == 1) ? d0 : ((l == 2) ? d1 : d2);
        if (m2 == l) { l += 1; if (l <= lend) continue; break; }
        if (m2 == l + 1) {
          float rt1, rt2, c, s;
          if (l == 1) {
            slaev2f(d0, e0, d1, rt1, rt2, c, s);
            ROT12(c, s)
            d0 = rt1; d1 = rt2; e0 = 0.f;
          } else {
            slaev2f(d1, e1, d2, rt1, rt2, c, s);
            ROT23(c, s)
            d1 = rt1; d2 = rt2; e1 = 0.f;
          }
          l += 2; if (l <= lend) continue; break;
        }
        if (jtot == nmaxit) break;
        jtot++;
        // full QL step: l=1, m2=3, lend=3
        float g = (d1 - p) / (2.f * e0);
        float r = lapy2f(g, 1.f);
        g = d2 - p + e0 / (g + copysignf(r, g));
        float s = 1.f, c = 1.f;
        p = 0.f;
        float c0, s0n, c1, s1n;
        {  // i = 2
          float f = s * e1;
          float bb = c * e1;
          slartgf(g, f, c, s, r);
          g = d2 - p;
          r = (d1 - g) * s + 2.f * c * bb;
          p = s * r;
          d2 = g + p;
          g = c * r - bb;
          c1 = c; s1n = -s;
        }
        {  // i = 1
          float f = s * e0;
          float bb = c * e0;
          slartgf(g, f, c, s, r);
          e1 = r;
          g = d1 - p;
          r = (d0 - g) * s + 2.f * c * bb;
          p = s * r;
          d1 = g + p;
          g = c * r - bb;
          c0 = c; s0n = -s;
        }
        ROT23(c1, s1n)
        ROT12(c0, s0n)
        d0 = d0 - p;
        e0 = g;
      }
    } else {
      // ---- QR iteration ----
      for (int it = 0; it < 128; ++it) {
        int m2 = lend;
        if (l != lend) {
          for (int mm = l; mm >= lend + 1; --mm) {
            float em  = (mm == 3) ? e1 : e0;
            float dm1 = (mm == 3) ? d2 : d1;
            float dm2 = (mm == 3) ? d1 : d0;
            float tst = em * em;
            if (tst <= (eps2 * fabsf(dm1)) * fabsf(dm2) + safmin) { m2 = mm; break; }
          }
        }
        if (m2 > lend) { if (m2 == 3) e1 = 0.f; else e0 = 0.f; }
        float p = (l == 1) ? d0 : ((l == 2) ? d1 : d2);
        if (m2 == l) { l -= 1; if (l >= lend) continue; break; }
        if (m2 == l - 1) {
          float rt1, rt2, c, s;
          if (l == 2) {
            slaev2f(d0, e0, d1, rt1, rt2, c, s);
            ROT12(c, s)
            d0 = rt1; d1 = rt2; e0 = 0.f;
          } else {
            slaev2f(d1, e1, d2, rt1, rt2, c, s);
            ROT23(c, s)
            d1 = rt1; d2 = rt2; e1 = 0.f;
          }
          l -= 2; if (l >= lend) continue; break;
        }
        if (jtot == nmaxit) break;
        jtot++;
        // full QR step: l=3, m2=1, lend=1
        float g = (d1 - p) / (2.f * e1);
        float r = lapy2f(g, 1.f);
        g = d0 - p + e1 / (g + copysignf(r, g));
        float s = 1.f, c = 1.f;
        p = 0.f;
        float c0, s0p, c1, s1p;
        {  // i = 1
          float f = s * e0;
          float bb = c * e0;
          slartgf(g, f, c, s, r);
          g = d0 - p;
          r = (d1 - g) * s + 2.f * c * bb;
          p = s * r;
          d0 = g + p;
          g = c * r - bb;
          c0 = c; s0p = s;
        }
        {  // i = 2
          float f = s * e1;
          float bb = c * e1;
          slartgf(g, f, c, s, r);
          e0 = r;
          g = d1 - p;
          r = (d2 - g) * s + 2.f * c * bb;
          p = s * r;
          d1 = g + p;
          g = c * r - bb;
          c1 = c; s1p = s;
        }
        ROT12(c0, s0p)
        ROT23(c1, s1p)
        d2 = d2 - p;
        e1 = g;
      }
    }
  }
  // ascending eigenvalue selection sort with column swaps
  {
    int k = 1; float p = d0;
    if (d1 < p) { k = 2; p = d1; }
    if (d2 < p) { k = 3; p = d2; }
    if (k == 2) {
      d1 = d0; d0 = p;
      float t;
      t = z00; z00 = z01; z01 = t;
      t = z10; z10 = z11; z11 = t;
      t = z20; z20 = z21; z21 = t;
    } else if (k == 3) {
      d2 = d0; d0 = p;
      float t;
      t = z00; z00 = z02; z02 = t;
      t = z10; z10 = z12; z12 = t;
      t = z20; z20 = z22; z22 = t;
    }
    k = 2; p = d1;
    if (d2 < p) { k = 3; p = d2; }
    if (k == 3) {
      d2 = d1; d1 = p;
      float t;
      t = z01; z01 = z02; z02 = t;
      t = z11; z11 = z12; z12 = t;
      t = z21; z21 = z22; z22 = t;
    }
  }
}

// ---------------- Kernel 1: KNN (block-per-point, 4 cooperating waves) ----------------
// 2048 blocks x 256 threads. Wave wv covers j-slice [wv*512, wv*512+512);
// each lane owns 8 CONSECUTIVE j's loaded as 6 x dwordx4 (24 floats).
// Self (j==p) is excluded upfront (key -> INF; self is provably global rank
// 0 at distance 0), so only 10 extraction rounds are needed and merged
// ranks 0..9 are directly the reference's knn[:,1:]. Wave-wide u64 min is
// done exactly as two u32 v_min butterflies (hi word, then lo word among
// hi-winners). Distance formula bitwise-identical (contract off); eigh path
// unchanged.

__global__ __launch_bounds__(256) void knn_normals_kernel(
    const float* __restrict__ pts,
    float* __restrict__ pxa, float* __restrict__ pya, float* __restrict__ pza,
    float* __restrict__ nxa, float* __restrict__ nya, float* __restrict__ nza) {
  __shared__ unsigned long long cand[4 * KNN];
  __shared__ int knn_sh[KNN];
  const int tid = threadIdx.x;
  const int lane = tid & 63;
  const int wv = tid >> 6;
  const int p = blockIdx.x;

  {
    float px = pts[3 * p], py = pts[3 * p + 1], pz = pts[3 * p + 2];
    if (tid == 0) { pxa[p] = px; pya[p] = py; pza[p] = pz; }

    // 8 consecutive points per lane: 24 floats = 6 float4 loads
    const int j0 = wv * 512 + lane * 8;
    const float4* p4 = (const float4*)(pts + 3 * (wv * 512));
    float4 a0 = p4[6 * lane + 0];
    float4 a1 = p4[6 * lane + 1];
    float4 a2 = p4[6 * lane + 2];
    float4 a3 = p4[6 * lane + 3];
    float4 a4 = p4[6 * lane + 4];
    float4 a5 = p4[6 * lane + 5];

    unsigned long long k0[8];
#define DISTK(t, X, Y, Z)                                                 \
    {                                                                     \
      int j = j0 + (t);                                                   \
      float dx = px - (X);                                                \
      float dy = py - (Y);                                                \
      float dz = pz - (Z);                                                \
      float sq = dx * dx;                                                 \
      sq = sq + dy * dy;                                                  \
      sq = sq + dz * dz;                                                  \
      unsigned long long key =                                            \
          (((unsigned long long)__float_as_uint(sq)) << 32) |             \
          (unsigned int)j;                                                \
      k0[t] = (j == p) ? 0xFFFFFFFFFFFFFFFFULL : key;                     \
    }
    DISTK(0, a0.x, a0.y, a0.z)
    DISTK(1, a0.w, a1.x, a1.y)
    DISTK(2, a1.z, a1.w, a2.x)
    DISTK(3, a2.y, a2.z, a2.w)
    DISTK(4, a3.x, a3.y, a3.z)
    DISTK(5, a3.w, a4.x, a4.y)
    DISTK(6, a4.z, a4.w, a5.x)
    DISTK(7, a5.y, a5.z, a5.w)
#undef DISTK

#define CE(a, b)                                                          \
    {                                                                     \
      unsigned long long lo = k0[a] < k0[b] ? k0[a] : k0[b];              \
      unsigned long long hi = k0[a] < k0[b] ? k0[b] : k0[a];              \
      k0[a] = lo; k0[b] = hi;                                             \
    }
    CE(0, 1) CE(2, 3) CE(4, 5) CE(6, 7)
    CE(0, 2) CE(1, 3) CE(4, 6) CE(5, 7)
    CE(1, 2) CE(5, 6) CE(0, 4) CE(3, 7)
    CE(1, 5) CE(2, 6)
    CE(1, 4) CE(3, 6)
    CE(2, 4) CE(3, 5)
    CE(3, 4)
#undef CE

    // 10 rounds: extract this wave's top-10 (keys unique -> single winner).
    // u64 wave-min as two u32 min-butterflies (exact).
    for (int r = 0; r < KNN; ++r) {
      unsigned hi0 = (unsigned)(k0[0] >> 32);
      unsigned lo0 = (unsigned)(k0[0] & 0xFFFFFFFFULL);
      unsigned mhi = hi0;
#pragma unroll
      for (int off = 32; off > 0; off >>= 1) {
        unsigned o = __shfl_xor(mhi, off, 64);
        mhi = o < mhi ? o : mhi;
      }
      unsigned mlo = (hi0 == mhi) ? lo0 : 0xFFFFFFFFu;
#pragma unroll
      for (int off = 32; off > 0; off >>= 1) {
        unsigned o = __shfl_xor(mlo, off, 64);
        mlo = o < mlo ? o : mlo;
      }
      if (lane == 0)
        cand[wv * KNN + r] = (((unsigned long long)mhi) << 32) | mlo;
      if (hi0 == mhi && lo0 == mlo) {  // unique winner lane pops
#pragma unroll
        for (int q = 0; q < 7; ++q) k0[q] = k0[q + 1];
        k0[7] = 0xFFFFFFFFFFFFFFFFULL;
      }
    }
  }
  __syncthreads();

  // Rank-merge the 40 candidates; ranks 0..9 are the KNN in top_k order.
  if (tid < 4 * KNN) {
    unsigned long long e = cand[tid];
    int rank = 0;
#pragma unroll
    for (int m = 0; m < 4 * KNN; ++m) rank += (cand[m] < e) ? 1 : 0;
    if (rank < KNN)
      knn_sh[rank] = (int)(unsigned int)(e & 0xFFFFFFFFULL);
  }
  __syncthreads();

  // ---- covariance + eigh for this block's point (thread 0) ----
  if (tid == 0) {
    float nx[KNN], ny[KNN], nz[KNN];
    float sx = 0.f, sy = 0.f, sz = 0.f;
#pragma unroll
    for (int t = 0; t < KNN; ++t) {
      int j = knn_sh[t];
      nx[t] = pts[3 * j]; ny[t] = pts[3 * j + 1]; nz[t] = pts[3 * j + 2];
      sx = sx + nx[t]; sy = sy + ny[t]; sz = sz + nz[t];
    }
    float mx = sx / 10.f, my = sy / 10.f, mz = sz / 10.f;
    float a11 = 0.f, a21 = 0.f, a31 = 0.f, a22 = 0.f, a32 = 0.f, a33 = 0.f;
#pragma unroll
    for (int t = 0; t < KNN; ++t) {
      float cx = nx[t] - mx, cy = ny[t] - my, cz = nz[t] - mz;
      a11 = a11 + cx * cx;
      a21 = a21 + cy * cx;
      a31 = a31 + cz * cx;
      a22 = a22 + cy * cy;
      a32 = a32 + cz * cy;
      a33 = a33 + cz * cz;
    }
    a11 = a11 / 10.f; a21 = a21 / 10.f; a31 = a31 / 10.f;
    a22 = a22 / 10.f; a32 = a32 / 10.f; a33 = a33 / 10.f;

    // SSYTD2 (uplo='L', n=3)
    float d0, d1, d2, e0, e1, tau1 = 0.f, v2 = 0.f;
    {
      float alpha = a21;
      float xnorm = fabsf(a31);
      if (xnorm == 0.f) {
        tau1 = 0.f; v2 = 0.f;
        d0 = a11; d1 = a22; d2 = a33; e0 = alpha; e1 = a32;
      } else {
        float beta = -copysignf(lapy2f(alpha, xnorm), alpha);
        tau1 = (beta - alpha) / beta;
        v2 = a31 * (1.f / (alpha - beta));  // DSCAL: reciprocal then multiply
        float y1 = tau1 * a22; y1 = y1 + tau1 * (a32 * v2);
        float y2 = tau1 * a32; y2 = y2 + (tau1 * v2) * a33;
        float dotv = y1; dotv = dotv + y2 * v2;
        float ac = -0.5f * tau1 * dotv;
        y1 = y1 + ac;
        y2 = y2 + ac * v2;
        float t1 = -y1, t2 = -1.f;
        a22 = (a22 + t1) + y1 * t2;
        a32 = (a32 + v2 * t1) + y2 * t2;
        float t1b = -y2, t2b = -v2;
        a33 = (a33 + v2 * t1b) + y2 * t2b;
        d0 = a11; d1 = a22; d2 = a33; e0 = beta; e1 = a32;
      }
    }
    float z00 = 1.f, z01 = 0.f, z02 = 0.f;
    float z10 = 0.f, z11 = 1.f, z12 = 0.f;
    float z20 = 0.f, z21 = 0.f, z22 = 1.f;
    ssteqr3_reg(d0, d1, d2, e0, e1,
                z00, z01, z02, z10, z11, z12, z20, z21, z22);
    if (tau1 != 0.f) {
      float w = tau1 * (z10 + v2 * z20);
      z10 = z10 - w;
      z20 = z20 - v2 * w;
    }
    nxa[p] = z00;
    nya[p] = z10;
    nza[p] = z20;
  }
}

// ---------------- Kernel 2: PPF, block-per-point ----------------
// 2048 blocks x 256 threads. Wave wv covers j-slice [wv*512, wv*512+512);
// each lane owns 4 consecutive j's per outer iter via 6 x dwordx4 loads.
// Cross products eliminated: normals are unit vectors, so
// |v x d|^2 = sq - (v.d)^2 and |ni x nj|^2 = 1 - (ni.nj)^2 (clamped at 0).
// Wave butterfly then 4x4 LDS partial reduce; one output per thread.

__device__ __forceinline__ float atan2_pos(float y, float x) {
#pragma clang fp contract(fast)
  // y >= 0; returns atan2(y, x) in [0, pi]; |err| <= 1e-5 rad
  float axx = fabsf(x);
  float mn = fminf(axx, y), mx = fmaxf(axx, y);
  float a = mn * __builtin_amdgcn_rcpf(mx);
  a = (mx == 0.f) ? 0.f : a;
  float s = a * a;
  float r = a * (0.9998660f +
           s * (-0.3302995f +
           s * (0.1801410f +
           s * (-0.0851330f +
           s * 0.0208351f))));
  r = (y > axx) ? 1.57079632679f - r : r;
  r = (x < 0.f) ? 3.14159265359f - r : r;
  return r;
}

__global__ __launch_bounds__(256) void ppf_kernel(
    const float* __restrict__ pxa, const float* __restrict__ pya,
    const float* __restrict__ pza, const float* __restrict__ nxa,
    const float* __restrict__ nya, const float* __restrict__ nza,
    const float* __restrict__ Wm, const float* __restrict__ bias,
    float* __restrict__ out) {
#pragma clang fp contract(fast)
  __shared__ float ps[4][4];
  const int tid = threadIdx.x;
  const int lane = tid & 63;
  const int wv = tid >> 6;
  const int i = blockIdx.x;

  float pxi = pxa[i], pyi = pya[i], pzi = pza[i];
  float ax = nxa[i], ay = nya[i], az = nza[i];

  float s0 = 0.f, s1 = 0.f, s2 = 0.f, s3 = 0.f;
#pragma unroll
  for (int it = 0; it < 2; ++it) {
    int j0 = wv * 512 + it * 256 + lane * 4;
    float4 jx = *(const float4*)(pxa + j0);
    float4 jy = *(const float4*)(pya + j0);
    float4 jz = *(const float4*)(pza + j0);
    float4 mx4 = *(const float4*)(nxa + j0);
    float4 my4 = *(const float4*)(nya + j0);
    float4 mz4 = *(const float4*)(nza + j0);
#define PAIR(PX, PY, PZ, BX, BY, BZ)                                      \
    {                                                                     \
      float dx = pxi - (PX);                                              \
      float dy = pyi - (PY);                                              \
      float dz = pzi - (PZ);                                              \
      float sq = dx * dx + dy * dy + dz * dz;                             \
      s0 += __builtin_amdgcn_sqrtf(sq);                                   \
      float da = ax * dx + ay * dy + az * dz;                             \
      s1 += atan2_pos(                                                    \
          __builtin_amdgcn_sqrtf(fmaxf(sq - da * da, 0.f)), da);          \
      float db = (BX) * dx + (BY) * dy + (BZ) * dz;                       \
      s2 += atan2_pos(                                                    \
          __builtin_amdgcn_sqrtf(fmaxf(sq - db * db, 0.f)), db);          \
      float dn = ax * (BX) + ay * (BY) + az * (BZ);                       \
      s3 += atan2_pos(                                                    \
          __builtin_amdgcn_sqrtf(fmaxf(1.f - dn * dn, 0.f)), dn);         \
    }
    PAIR(jx.x, jy.x, jz.x, mx4.x, my4.x, mz4.x)
    PAIR(jx.y, jy.y, jz.y, mx4.y, my4.y, mz4.y)
    PAIR(jx.z, jy.z, jz.z, mx4.z, my4.z, mz4.z)
    PAIR(jx.w, jy.w, jz.w, mx4.w, my4.w, mz4.w)
#undef PAIR
  }

  // wave butterfly reduce, then cross-wave reduce via 4x4 LDS partials
#pragma unroll
  for (int off = 1; off < 64; off <<= 1) {
    s0 += __shfl_xor(s0, off, 64);
    s1 += __shfl_xor(s1, off, 64);
    s2 += __shfl_xor(s2, off, 64);
    s3 += __shfl_xor(s3, off, 64);
  }
  if (lane == 0) { ps[wv][0] = s0; ps[wv][1] = s1; ps[wv][2] = s2; ps[wv][3] = s3; }
  __syncthreads();

  const float inv = 1.f / 2048.f;  // power of two: identical to /2048
  float f0 = ((ps[0][0] + ps[1][0]) + (ps[2][0] + ps[3][0])) * inv;
  float f1 = ((ps[0][1] + ps[1][1]) + (ps[2][1] + ps[3][1])) * inv;
  float f2 = ((ps[0][2] + ps[1][2]) + (ps[2][2] + ps[3][2])) * inv;
  float f3 = ((ps[0][3] + ps[1][3]) + (ps[2][3] + ps[3][3])) * inv;

  // epilogue: one output per thread (W row = exactly one float4)
  float4 w = ((const float4*)Wm)[tid];
  float r = (((f0 * w.x + f1 * w.y) + f2 * w.z) + f3 * w.w) + bias[tid];
  out[(size_t)i * NOUT + tid] = r;
}

// ---------------- launcher ----------------

extern "C" void kernel_launch(void* const* d_in, const int* in_sizes, int n_in,
                              void* d_out, int out_size, void* d_ws, size_t ws_size,
                              hipStream_t stream) {
  const float* pts = (const float*)d_in[0];   // (1,2048,3) fp32
  const float* Wm  = (const float*)d_in[1];   // (256,4) fp32
  const float* bs  = (const float*)d_in[2];   // (256,) fp32
  float* out = (float*)d_out;                 // (1,2048,256) fp32

  float* pxa = (float*)d_ws;                  // 6 SoA arrays of 2048 floats
  float* pya = pxa + NPTS;
  float* pza = pya + NPTS;
  float* nxa = pza + NPTS;
  float* nya = nxa + NPTS;
  float* nza = nya + NPTS;

  knn_normals_kernel<<<NPTS, 256, 0, stream>>>(pts, pxa, pya, pza, nxa, nya, nza);
  ppf_kernel<<<NPTS, 256, 0, stream>>>(pxa, pya, pza, nxa, nya, nza, Wm, bs, out);
}

// Round 3
// 92.363 us; speedup vs baseline: 1.1945x; 1.0346x over previous
//
#include <hip/hip_runtime.h>
#include <math.h>

// Default: no FMA contraction — KNN distance order and the LAPACK-faithful
// eigh path must match the reference bitwise. The tolerant PPF path opts
// back into contract(fast) locally.
#pragma clang fp contract(off)

#define NPTS 2048
#define KNN 10
#define NOUT 256

// ---------------- LAPACK-faithful fp32 helpers ----------------

__device__ __forceinline__ float lapy2f(float x, float y) {
  float xa = fabsf(x), ya = fabsf(y);
  float w = fmaxf(xa, ya), z = fminf(xa, ya);
  if (z == 0.f) return w;
  float t = z / w;
  return w * sqrtf(1.f + t * t);
}

// SLARTG, LAPACK >= 3.10 convention (modern OpenBLAS / numpy wheels).
__device__ __forceinline__ void slartgf(float f, float g, float& c, float& s, float& r) {
  if (g == 0.f) { c = 1.f; s = 0.f; r = f; }
  else if (f == 0.f) { c = 0.f; s = copysignf(1.f, g); r = fabsf(g); }
  else {
    float d = sqrtf(f * f + g * g);
    float p = 1.f / d;
    c = fabsf(f) * p;
    s = g * copysignf(p, f);
    r = copysignf(d, f);
  }
}

__device__ __forceinline__ void slaev2f(float a, float b, float c,
                                        float& rt1, float& rt2, float& cs1, float& sn1) {
  float sm = a + c;
  float df = a - c;
  float adf = fabsf(df);
  float tb = b + b;
  float ab = fabsf(tb);
  float acmx, acmn;
  if (fabsf(a) > fabsf(c)) { acmx = a; acmn = c; } else { acmx = c; acmn = a; }
  float rt;
  if (adf > ab)      { float t = ab / adf; rt = adf * sqrtf(1.f + t * t); }
  else if (adf < ab) { float t = adf / ab; rt = ab * sqrtf(1.f + t * t); }
  else               { rt = ab * sqrtf(2.f); }
  int sgn1;
  if (sm < 0.f) {
    rt1 = 0.5f * (sm - rt); sgn1 = -1;
    rt2 = (acmx / rt1) * acmn - (b / rt1) * b;
  } else if (sm > 0.f) {
    rt1 = 0.5f * (sm + rt); sgn1 = 1;
    rt2 = (acmx / rt1) * acmn - (b / rt1) * b;
  } else {
    rt1 = 0.5f * rt; rt2 = -0.5f * rt; sgn1 = 1;
  }
  int sgn2; float cs;
  if (df >= 0.f) { cs = df + rt; sgn2 = 1; } else { cs = df - rt; sgn2 = -1; }
  float acs = fabsf(cs);
  if (acs > ab) {
    float ct = -tb / cs;
    sn1 = 1.f / sqrtf(1.f + ct * ct);
    cs1 = ct * sn1;
  } else {
    if (ab == 0.f) { cs1 = 1.f; sn1 = 0.f; }
    else {
      float tn = -cs / tb;
      cs1 = 1.f / sqrtf(1.f + tn * tn);
      sn1 = tn * cs1;
    }
  }
  if (sgn1 == sgn2) { float tn = cs1; cs1 = -sn1; sn1 = tn; }
}

// Column rotations on the scalarized 3x3 eigenvector matrix (z[row][col]).
#define ROT12(c, s) {                                         \
    float t_;                                                 \
    t_ = z01; z01 = (c) * t_ - (s) * z00; z00 = (s) * t_ + (c) * z00; \
    t_ = z11; z11 = (c) * t_ - (s) * z10; z10 = (s) * t_ + (c) * z10; \
    t_ = z21; z21 = (c) * t_ - (s) * z20; z20 = (s) * t_ + (c) * z20; }
#define ROT23(c, s) {                                         \
    float t_;                                                 \
    t_ = z02; z02 = (c) * t_ - (s) * z01; z01 = (s) * t_ + (c) * z01; \
    t_ = z12; z12 = (c) * t_ - (s) * z11; z11 = (s) * t_ + (c) * z11; \
    t_ = z22; z22 = (c) * t_ - (s) * z21; z21 = (s) * t_ + (c) * z21; }

// SSTEQR('I', n=3), fully scalarized: all state in VGPRs, zero scratch.
__device__ __forceinline__ void ssteqr3_reg(
    float& d0, float& d1, float& d2, float& e0, float& e1,
    float& z00, float& z01, float& z02,
    float& z10, float& z11, float& z12,
    float& z20, float& z21, float& z22) {
  const float eps = 5.9604645e-8f;
  const float eps2 = eps * eps;
  const float safmin = 1.1754944e-38f;
  const int nmaxit = 90;
  int jtot = 0;
  int l1 = 1;
  for (int og = 0; og < 4; ++og) {
    if (l1 > 3) break;
    if (l1 == 2) e0 = 0.f;
    else if (l1 == 3) e1 = 0.f;
    int m = 3;
    if (l1 == 1) {
      float t = fabsf(e0);
      if (t == 0.f) m = 1;
      else if (t <= (sqrtf(fabsf(d0)) * sqrtf(fabsf(d1))) * eps) { e0 = 0.f; m = 1; }
      else {
        float t2 = fabsf(e1);
        if (t2 == 0.f) m = 2;
        else if (t2 <= (sqrtf(fabsf(d1)) * sqrtf(fabsf(d2))) * eps) { e1 = 0.f; m = 2; }
      }
    } else if (l1 == 2) {
      float t = fabsf(e1);
      if (t == 0.f) m = 2;
      else if (t <= (sqrtf(fabsf(d1)) * sqrtf(fabsf(d2))) * eps) { e1 = 0.f; m = 2; }
    }
    int l = l1, lend = m;
    l1 = m + 1;
    if (lend == l) continue;
    {
      float dlend = (lend == 1) ? d0 : ((lend == 2) ? d1 : d2);
      float dl = (l == 1) ? d0 : ((l == 2) ? d1 : d2);
      if (fabsf(dlend) < fabsf(dl)) { int t = lend; lend = l; l = t; }
    }
    if (lend > l) {
      // ---- QL iteration ----
      for (int it = 0; it < 128; ++it) {
        int m2 = lend;
        if (l != lend) {
          for (int mm = l; mm <= lend - 1; ++mm) {
            float em  = (mm == 1) ? e0 : e1;
            float dm1 = (mm == 1) ? d0 : d1;
            float dm  = (mm == 1) ? d1 : d2;
            float tst = em * em;
            if (tst <= (eps2 * fabsf(dm1)) * fabsf(dm) + safmin) { m2 = mm; break; }
          }
        }
        if (m2 < lend) { if (m2 == 1) e0 = 0.f; else e1 = 0.f; }
        float p = (l == 1) ? d0 : ((l == 2) ? d1 : d2);
        if (m2 == l) { l += 1; if (l <= lend) continue; break; }
        if (m2 == l + 1) {
          float rt1, rt2, c, s;
          if (l == 1) {
            slaev2f(d0, e0, d1, rt1, rt2, c, s);
            ROT12(c, s)
            d0 = rt1; d1 = rt2; e0 = 0.f;
          } else {
            slaev2f(d1, e1, d2, rt1, rt2, c, s);
            ROT23(c, s)
            d1 = rt1; d2 = rt2; e1 = 0.f;
          }
          l += 2; if (l <= lend) continue; break;
        }
        if (jtot == nmaxit) break;
        jtot++;
        // full QL step: l=1, m2=3, lend=3
        float g = (d1 - p) / (2.f * e0);
        float r = lapy2f(g, 1.f);
        g = d2 - p + e0 / (g + copysignf(r, g));
        float s = 1.f, c = 1.f;
        p = 0.f;
        float c0, s0n, c1, s1n;
        {  // i = 2
          float f = s * e1;
          float bb = c * e1;
          slartgf(g, f, c, s, r);
          g = d2 - p;
          r = (d1 - g) * s + 2.f * c * bb;
          p = s * r;
          d2 = g + p;
          g = c * r - bb;
          c1 = c; s1n = -s;
        }
        {  // i = 1
          float f = s * e0;
          float bb = c * e0;
          slartgf(g, f, c, s, r);
          e1 = r;
          g = d1 - p;
          r = (d0 - g) * s + 2.f * c * bb;
          p = s * r;
          d1 = g + p;
          g = c * r - bb;
          c0 = c; s0n = -s;
        }
        ROT23(c1, s1n)
        ROT12(c0, s0n)
        d0 = d0 - p;
        e0 = g;
      }
    } else {
      // ---- QR iteration ----
      for (int it = 0; it < 128; ++it) {
        int m2 = lend;
        if (l != lend) {
          for (int mm = l; mm >= lend + 1; --mm) {
            float em  = (mm == 3) ? e1 : e0;
            float dm1 = (mm == 3) ? d2 : d1;
            float dm2 = (mm == 3) ? d1 : d0;
            float tst = em * em;
            if (tst <= (eps2 * fabsf(dm1)) * fabsf(dm2) + safmin) { m2 = mm; break; }
          }
        }
        if (m2 > lend) { if (m2 == 3) e1 = 0.f; else e0 = 0.f; }
        float p = (l == 1) ? d0 : ((l == 2) ? d1 : d2);
        if (m2 == l) { l -= 1; if (l >= lend) continue; break; }
        if (m2 == l - 1) {
          float rt1, rt2, c, s;
          if (l == 2) {
            slaev2f(d0, e0, d1, rt1, rt2, c, s);
            ROT12(c, s)
            d0 = rt1; d1 = rt2; e0 = 0.f;
          } else {
            slaev2f(d1, e1, d2, rt1, rt2, c, s);
            ROT23(c, s)
            d1 = rt1; d2 = rt2; e1 = 0.f;
          }
          l -= 2; if (l >= lend) continue; break;
        }
        if (jtot == nmaxit) break;
        jtot++;
        // full QR step: l=3, m2=1, lend=1
        float g = (d1 - p) / (2.f * e1);
        float r = lapy2f(g, 1.f);
        g = d0 - p + e1 / (g + copysignf(r, g));
        float s = 1.f, c = 1.f;
        p = 0.f;
        float c0, s0p, c1, s1p;
        {  // i = 1
          float f = s * e0;
          float bb = c * e0;
          slartgf(g, f, c, s, r);
          g = d0 - p;
          r = (d1 - g) * s + 2.f * c * bb;
          p = s * r;
          d0 = g + p;
          g = c * r - bb;
          c0 = c; s0p = s;
        }
        {  // i = 2
          float f = s * e1;
          float bb = c * e1;
          slartgf(g, f, c, s, r);
          e0 = r;
          g = d1 - p;
          r = (d2 - g) * s + 2.f * c * bb;
          p = s * r;
          d1 = g + p;
          g = c * r - bb;
          c1 = c; s1p = s;
        }
        ROT12(c0, s0p)
        ROT23(c1, s1p)
        d2 = d2 - p;
        e1 = g;
      }
    }
  }
  // ascending eigenvalue selection sort with column swaps
  {
    int k = 1; float p = d0;
    if (d1 < p) { k = 2; p = d1; }
    if (d2 < p) { k = 3; p = d2; }
    if (k == 2) {
      d1 = d0; d0 = p;
      float t;
      t = z00; z00 = z01; z01 = t;
      t = z10; z10 = z11; z11 = t;
      t = z20; z20 = z21; z21 = t;
    } else if (k == 3) {
      d2 = d0; d0 = p;
      float t;
      t = z00; z00 = z02; z02 = t;
      t = z10; z10 = z12; z12 = t;
      t = z20; z20 = z22; z22 = t;
    }
    k = 2; p = d1;
    if (d2 < p) { k = 3; p = d2; }
    if (k == 3) {
      d2 = d1; d1 = p;
      float t;
      t = z01; z01 = z02; z02 = t;
      t = z11; z11 = z12; z12 = t;
      t = z21; z21 = z22; z22 = t;
    }
  }
}

// ---------------- Kernel 1: KNN (block-per-point, 4 cooperating waves) ----------------
// 2048 blocks x 256 threads. Wave wv covers j-slice [wv*512, wv*512+512);
// each lane owns 8 CONSECUTIVE j's loaded as 6 x dwordx4 (24 floats).
// Self (j==p) excluded upfront (key -> INF). 10 extraction rounds give the
// wave's top-10; rank-merge of 4x10 candidates reproduces top_k order.
// Round extraction: hi-word (distance bits) min-butterfly, then __ballot to
// find the winner lane; the lo word comes from a single readlane. Only on a
// genuine hi-word tie (bit-identical distances, ~never) does the exact
// lo-word butterfly fallback run — result is bit-identical to the full u64
// min in all cases. Distance formula bitwise-identical (contract off); eigh
// path unchanged.

__global__ __launch_bounds__(256) void knn_normals_kernel(
    const float* __restrict__ pts,
    float* __restrict__ pxa, float* __restrict__ pya, float* __restrict__ pza,
    float* __restrict__ nxa, float* __restrict__ nya, float* __restrict__ nza) {
  __shared__ unsigned long long cand[4 * KNN];
  __shared__ int knn_sh[KNN];
  const int tid = threadIdx.x;
  const int lane = tid & 63;
  const int wv = tid >> 6;
  const int p = blockIdx.x;

  {
    float px = pts[3 * p], py = pts[3 * p + 1], pz = pts[3 * p + 2];
    if (tid == 0) { pxa[p] = px; pya[p] = py; pza[p] = pz; }

    // 8 consecutive points per lane: 24 floats = 6 float4 loads
    const int j0 = wv * 512 + lane * 8;
    const float4* p4 = (const float4*)(pts + 3 * (wv * 512));
    float4 a0 = p4[6 * lane + 0];
    float4 a1 = p4[6 * lane + 1];
    float4 a2 = p4[6 * lane + 2];
    float4 a3 = p4[6 * lane + 3];
    float4 a4 = p4[6 * lane + 4];
    float4 a5 = p4[6 * lane + 5];

    unsigned long long k0[8];
#define DISTK(t, X, Y, Z)                                                 \
    {                                                                     \
      int j = j0 + (t);                                                   \
      float dx = px - (X);                                                \
      float dy = py - (Y);                                                \
      float dz = pz - (Z);                                                \
      float sq = dx * dx;                                                 \
      sq = sq + dy * dy;                                                  \
      sq = sq + dz * dz;                                                  \
      unsigned long long key =                                            \
          (((unsigned long long)__float_as_uint(sq)) << 32) |             \
          (unsigned int)j;                                                \
      k0[t] = (j == p) ? 0xFFFFFFFFFFFFFFFFULL : key;                     \
    }
    DISTK(0, a0.x, a0.y, a0.z)
    DISTK(1, a0.w, a1.x, a1.y)
    DISTK(2, a1.z, a1.w, a2.x)
    DISTK(3, a2.y, a2.z, a2.w)
    DISTK(4, a3.x, a3.y, a3.z)
    DISTK(5, a3.w, a4.x, a4.y)
    DISTK(6, a4.z, a4.w, a5.x)
    DISTK(7, a5.y, a5.z, a5.w)
#undef DISTK

#define CE(a, b)                                                          \
    {                                                                     \
      unsigned long long lo = k0[a] < k0[b] ? k0[a] : k0[b];              \
      unsigned long long hi = k0[a] < k0[b] ? k0[b] : k0[a];              \
      k0[a] = lo; k0[b] = hi;                                             \
    }
    CE(0, 1) CE(2, 3) CE(4, 5) CE(6, 7)
    CE(0, 2) CE(1, 3) CE(4, 6) CE(5, 7)
    CE(1, 2) CE(5, 6) CE(0, 4) CE(3, 7)
    CE(1, 5) CE(2, 6)
    CE(1, 4) CE(3, 6)
    CE(2, 4) CE(3, 5)
    CE(3, 4)
#undef CE

    // 10 rounds: extract this wave's top-10 (keys unique -> single winner).
    for (int r = 0; r < KNN; ++r) {
      unsigned hi0 = (unsigned)(k0[0] >> 32);
      unsigned lo0 = (unsigned)(k0[0] & 0xFFFFFFFFULL);
      unsigned mhi = hi0;
#pragma unroll
      for (int off = 32; off > 0; off >>= 1) {
        unsigned o = __shfl_xor(mhi, off, 64);
        mhi = o < mhi ? o : mhi;
      }
      unsigned long long tied = __ballot(hi0 == mhi);
      unsigned long long winkey;
      if (__popcll(tied) == 1) {          // wave-uniform branch, ~always taken
        int wl = (int)__builtin_ctzll(tied);
        unsigned wlo = (unsigned)__shfl((int)lo0, wl, 64);
        winkey = (((unsigned long long)mhi) << 32) | wlo;
      } else {                            // exact tie fallback (bit-equal dists)
        unsigned mlo = (hi0 == mhi) ? lo0 : 0xFFFFFFFFu;
#pragma unroll
        for (int off = 32; off > 0; off >>= 1) {
          unsigned o = __shfl_xor(mlo, off, 64);
          mlo = o < mlo ? o : mlo;
        }
        winkey = (((unsigned long long)mhi) << 32) | mlo;
      }
      if (lane == 0) cand[wv * KNN + r] = winkey;
      if (k0[0] == winkey) {  // unique winner lane pops
#pragma unroll
        for (int q = 0; q < 7; ++q) k0[q] = k0[q + 1];
        k0[7] = 0xFFFFFFFFFFFFFFFFULL;
      }
    }
  }
  __syncthreads();

  // Rank-merge the 40 candidates; ranks 0..9 are the KNN in top_k order.
  if (tid < 4 * KNN) {
    unsigned long long e = cand[tid];
    int rank = 0;
#pragma unroll
    for (int m = 0; m < 4 * KNN; ++m) rank += (cand[m] < e) ? 1 : 0;
    if (rank < KNN)
      knn_sh[rank] = (int)(unsigned int)(e & 0xFFFFFFFFULL);
  }
  __syncthreads();

  // ---- covariance + eigh for this block's point (thread 0) ----
  if (tid == 0) {
    float nx[KNN], ny[KNN], nz[KNN];
    float sx = 0.f, sy = 0.f, sz = 0.f;
#pragma unroll
    for (int t = 0; t < KNN; ++t) {
      int j = knn_sh[t];
      nx[t] = pts[3 * j]; ny[t] = pts[3 * j + 1]; nz[t] = pts[3 * j + 2];
      sx = sx + nx[t]; sy = sy + ny[t]; sz = sz + nz[t];
    }
    float mx = sx / 10.f, my = sy / 10.f, mz = sz / 10.f;
    float a11 = 0.f, a21 = 0.f, a31 = 0.f, a22 = 0.f, a32 = 0.f, a33 = 0.f;
#pragma unroll
    for (int t = 0; t < KNN; ++t) {
      float cx = nx[t] - mx, cy = ny[t] - my, cz = nz[t] - mz;
      a11 = a11 + cx * cx;
      a21 = a21 + cy * cx;
      a31 = a31 + cz * cx;
      a22 = a22 + cy * cy;
      a32 = a32 + cz * cy;
      a33 = a33 + cz * cz;
    }
    a11 = a11 / 10.f; a21 = a21 / 10.f; a31 = a31 / 10.f;
    a22 = a22 / 10.f; a32 = a32 / 10.f; a33 = a33 / 10.f;

    // SSYTD2 (uplo='L', n=3)
    float d0, d1, d2, e0, e1, tau1 = 0.f, v2 = 0.f;
    {
      float alpha = a21;
      float xnorm = fabsf(a31);
      if (xnorm == 0.f) {
        tau1 = 0.f; v2 = 0.f;
        d0 = a11; d1 = a22; d2 = a33; e0 = alpha; e1 = a32;
      } else {
        float beta = -copysignf(lapy2f(alpha, xnorm), alpha);
        tau1 = (beta - alpha) / beta;
        v2 = a31 * (1.f / (alpha - beta));  // DSCAL: reciprocal then multiply
        float y1 = tau1 * a22; y1 = y1 + tau1 * (a32 * v2);
        float y2 = tau1 * a32; y2 = y2 + (tau1 * v2) * a33;
        float dotv = y1; dotv = dotv + y2 * v2;
        float ac = -0.5f * tau1 * dotv;
        y1 = y1 + ac;
        y2 = y2 + ac * v2;
        float t1 = -y1, t2 = -1.f;
        a22 = (a22 + t1) + y1 * t2;
        a32 = (a32 + v2 * t1) + y2 * t2;
        float t1b = -y2, t2b = -v2;
        a33 = (a33 + v2 * t1b) + y2 * t2b;
        d0 = a11; d1 = a22; d2 = a33; e0 = beta; e1 = a32;
      }
    }
    float z00 = 1.f, z01 = 0.f, z02 = 0.f;
    float z10 = 0.f, z11 = 1.f, z12 = 0.f;
    float z20 = 0.f, z21 = 0.f, z22 = 1.f;
    ssteqr3_reg(d0, d1, d2, e0, e1,
                z00, z01, z02, z10, z11, z12, z20, z21, z22);
    if (tau1 != 0.f) {
      float w = tau1 * (z10 + v2 * z20);
      z10 = z10 - w;
      z20 = z20 - v2 * w;
    }
    nxa[p] = z00;
    nya[p] = z10;
    nza[p] = z20;
  }
}

// ---------------- Kernel 2: PPF, block-per-point ----------------
// 2048 blocks x 256 threads. Wave wv covers j-slice [wv*512, wv*512+512);
// each lane owns 4 consecutive j's per outer iter via 6 x dwordx4 loads.
// Cross products eliminated: normals are unit vectors, so
// |v x d|^2 = sq - (v.d)^2 and |ni x nj|^2 = 1 - (ni.nj)^2 (clamped at 0).
// Wave butterfly then 4x4 LDS partial reduce; one output per thread.

__device__ __forceinline__ float atan2_pos(float y, float x) {
#pragma clang fp contract(fast)
  // y >= 0; returns atan2(y, x) in [0, pi]; |err| <= 1e-5 rad
  float axx = fabsf(x);
  float mn = fminf(axx, y), mx = fmaxf(axx, y);
  float a = mn * __builtin_amdgcn_rcpf(mx);
  a = (mx == 0.f) ? 0.f : a;
  float s = a * a;
  float r = a * (0.9998660f +
           s * (-0.3302995f +
           s * (0.1801410f +
           s * (-0.0851330f +
           s * 0.0208351f))));
  r = (y > axx) ? 1.57079632679f - r : r;
  r = (x < 0.f) ? 3.14159265359f - r : r;
  return r;
}

__global__ __launch_bounds__(256) void ppf_kernel(
    const float* __restrict__ pxa, const float* __restrict__ pya,
    const float* __restrict__ pza, const float* __restrict__ nxa,
    const float* __restrict__ nya, const float* __restrict__ nza,
    const float* __restrict__ Wm, const float* __restrict__ bias,
    float* __restrict__ out) {
#pragma clang fp contract(fast)
  __shared__ float ps[4][4];
  const int tid = threadIdx.x;
  const int lane = tid & 63;
  const int wv = tid >> 6;
  const int i = blockIdx.x;

  float pxi = pxa[i], pyi = pya[i], pzi = pza[i];
  float ax = nxa[i], ay = nya[i], az = nza[i];

  float s0 = 0.f, s1 = 0.f, s2 = 0.f, s3 = 0.f;
#pragma unroll
  for (int it = 0; it < 2; ++it) {
    int j0 = wv * 512 + it * 256 + lane * 4;
    float4 jx = *(const float4*)(pxa + j0);
    float4 jy = *(const float4*)(pya + j0);
    float4 jz = *(const float4*)(pza + j0);
    float4 mx4 = *(const float4*)(nxa + j0);
    float4 my4 = *(const float4*)(nya + j0);
    float4 mz4 = *(const float4*)(nza + j0);
#define PAIR(PX, PY, PZ, BX, BY, BZ)                                      \
    {                                                                     \
      float dx = pxi - (PX);                                              \
      float dy = pyi - (PY);                                              \
      float dz = pzi - (PZ);                                              \
      float sq = dx * dx + dy * dy + dz * dz;                             \
      s0 += __builtin_amdgcn_sqrtf(sq);                                   \
      float da = ax * dx + ay * dy + az * dz;                             \
      s1 += atan2_pos(                                                    \
          __builtin_amdgcn_sqrtf(fmaxf(sq - da * da, 0.f)), da);          \
      float db = (BX) * dx + (BY) * dy + (BZ) * dz;                       \
      s2 += atan2_pos(                                                    \
          __builtin_amdgcn_sqrtf(fmaxf(sq - db * db, 0.f)), db);          \
      float dn = ax * (BX) + ay * (BY) + az * (BZ);                       \
      s3 += atan2_pos(                                                    \
          __builtin_amdgcn_sqrtf(fmaxf(1.f - dn * dn, 0.f)), dn);         \
    }
    PAIR(jx.x, jy.x, jz.x, mx4.x, my4.x, mz4.x)
    PAIR(jx.y, jy.y, jz.y, mx4.y, my4.y, mz4.y)
    PAIR(jx.z, jy.z, jz.z, mx4.z, my4.z, mz4.z)
    PAIR(jx.w, jy.w, jz.w, mx4.w, my4.w, mz4.w)
#undef PAIR
  }

  // wave butterfly reduce, then cross-wave reduce via 4x4 LDS partials
#pragma unroll
  for (int off = 1; off < 64; off <<= 1) {
    s0 += __shfl_xor(s0, off, 64);
    s1 += __shfl_xor(s1, off, 64);
    s2 += __shfl_xor(s2, off, 64);
    s3 += __shfl_xor(s3, off, 64);
  }
  if (lane == 0) { ps[wv][0] = s0; ps[wv][1] = s1; ps[wv][2] = s2; ps[wv][3] = s3; }
  __syncthreads();

  const float inv = 1.f / 2048.f;  // power of two: identical to /2048
  float f0 = ((ps[0][0] + ps[1][0]) + (ps[2][0] + ps[3][0])) * inv;
  float f1 = ((ps[0][1] + ps[1][1]) + (ps[2][1] + ps[3][1])) * inv;
  float f2 = ((ps[0][2] + ps[1][2]) + (ps[2][2] + ps[3][2])) * inv;
  float f3 = ((ps[0][3] + ps[1][3]) + (ps[2][3] + ps[3][3])) * inv;

  // epilogue: one output per thread (W row = exactly one float4)
  float4 w = ((const float4*)Wm)[tid];
  float r = (((f0 * w.x + f1 * w.y) + f2 * w.z) + f3 * w.w) + bias[tid];
  out[(size_t)i * NOUT + tid] = r;
}

// ---------------- launcher ----------------

extern "C" void kernel_launch(void* const* d_in, const int* in_sizes, int n_in,
                              void* d_out, int out_size, void* d_ws, size_t ws_size,
                              hipStream_t stream) {
  const float* pts = (const float*)d_in[0];   // (1,2048,3) fp32
  const float* Wm  = (const float*)d_in[1];   // (256,4) fp32
  const float* bs  = (const float*)d_in[2];   // (256,) fp32
  float* out = (float*)d_out;                 // (1,2048,256) fp32

  float* pxa = (float*)d_ws;                  // 6 SoA arrays of 2048 floats
  float* pya = pxa + NPTS;
  float* pza = pya + NPTS;
  float* nxa = pza + NPTS;
  float* nya = nxa + NPTS;
  float* nza = nya + NPTS;

  knn_normals_kernel<<<NPTS, 256, 0, stream>>>(pts, pxa, pya, pza, nxa, nya, nza);
  ppf_kernel<<<NPTS, 256, 0, stream>>>(pxa, pya, pza, nxa, nya, nza, Wm, bs, out);
}